// Round 1
// baseline (240.240 us; speedup 1.0000x reference)
//
#include <hip/hip_runtime.h>
#include <math.h>

// ---------------------------------------------------------------------------
// Cosine_PredictingModule: per-edge cosine + tiny MLP on MI355X.
//
// Restructuring: cat@W1 = heads@W1a + tails@W1b + cos*W1[128].
//   K1: fp32->bf16 node tables + per-node L2 norms (wave/node).
//   K2: per-node projections P = h @ W1x via bf16 MFMA 16x16x32 (fp32 accum),
//       stored bf16.
//   K3: per-edge gather of (h,t,Pc,Pp) rows + cosine + fused MLP epilogue.
//       16 lanes per edge, 4 dims per lane (ushort4 = 8B loads, coalesced
//       128B/row); reductions are 4 __shfl_xor steps within 16-lane rows.
// ---------------------------------------------------------------------------

typedef __attribute__((ext_vector_type(8))) short bf16x8;
typedef __attribute__((ext_vector_type(4))) float f32x4;
typedef __attribute__((ext_vector_type(4))) unsigned short ushort4_t;
typedef __attribute__((ext_vector_type(4))) float float4_t;

__device__ __forceinline__ float bf2f(unsigned short u) {
    return __uint_as_float(((unsigned int)u) << 16);
}
__device__ __forceinline__ unsigned short f2bf(float f) {
    unsigned int x = __float_as_uint(f);
    // round-to-nearest-even
    return (unsigned short)((x + 0x7fffu + ((x >> 16) & 1u)) >> 16);
}

// K1: one wave per node: bf16 copy + L2 norm (norm from fp32, matches ref).
__global__ __launch_bounds__(256) void convert_norm(
    const float* __restrict__ h, unsigned short* __restrict__ hb,
    float* __restrict__ norms, int n)
{
    int wid  = (blockIdx.x * 256 + threadIdx.x) >> 6;
    int lane = threadIdx.x & 63;
    if (wid >= n) return;
    float v = h[(long)wid * 64 + lane];
    hb[(long)wid * 64 + lane] = f2bf(v);
    float ss = v * v;
    ss += __shfl_xor(ss, 32);
    ss += __shfl_xor(ss, 16);
    ss += __shfl_xor(ss, 8);
    ss += __shfl_xor(ss, 4);
    ss += __shfl_xor(ss, 2);
    ss += __shfl_xor(ss, 1);
    if (lane == 0) norms[wid] = sqrtf(ss);
}

// K2: proj[n][0:64] = h[n][0:64] @ W1[w_off:w_off+64][0:64], bf16 MFMA.
// Per block: 64 nodes (4 waves x 16 rows), each wave does 4 N-tiles x 2 K-steps.
__global__ __launch_bounds__(256) void proj_mfma(
    const unsigned short* __restrict__ hb, const float* __restrict__ W1,
    unsigned short* __restrict__ proj, int n, int w_off)
{
    int wave = threadIdx.x >> 6;
    int lane = threadIdx.x & 63;
    int node0 = blockIdx.x * 64 + wave * 16;
    if (node0 >= n) return;          // n % 16 == 0 for this problem
    int m = lane & 15, quad = lane >> 4;

    // A fragments: A[m=lane&15][k=quad*8+j], 16B contiguous per lane.
    bf16x8 afrag[2];
#pragma unroll
    for (int ks = 0; ks < 2; ks++)
        afrag[ks] = *reinterpret_cast<const bf16x8*>(
            hb + (long)(node0 + m) * 64 + ks * 32 + quad * 8);

    f32x4 acc[4];
#pragma unroll
    for (int nt = 0; nt < 4; nt++) acc[nt] = (f32x4){0.f, 0.f, 0.f, 0.f};

#pragma unroll
    for (int nt = 0; nt < 4; nt++) {
#pragma unroll
        for (int ks = 0; ks < 2; ks++) {
            // B[k=quad*8+j][nn=lane&15]; W1 is tiny (33KB) -> L1/L2 resident.
            bf16x8 b;
#pragma unroll
            for (int j = 0; j < 8; j++) {
                int k = ks * 32 + quad * 8 + j;
                b[j] = (short)f2bf(W1[(w_off + k) * 64 + nt * 16 + m]);
            }
            acc[nt] = __builtin_amdgcn_mfma_f32_16x16x32_bf16(
                afrag[ks], b, acc[nt], 0, 0, 0);
        }
    }

    // C/D layout: col = lane&15, row = quad*4 + reg  [verified m89/m91]
#pragma unroll
    for (int nt = 0; nt < 4; nt++)
#pragma unroll
        for (int r = 0; r < 4; r++) {
            int row = quad * 4 + r, col = nt * 16 + m;
            proj[(long)(node0 + row) * 64 + col] = f2bf(acc[nt][r]);
        }
}

// K3: edge kernel. 4 edges per wave, 16 lanes per edge, 4 dims per lane.
__global__ __launch_bounds__(256) void edge_mlp(
    const unsigned short* __restrict__ hbc, const unsigned short* __restrict__ hbp,
    const unsigned short* __restrict__ pc,  const unsigned short* __restrict__ pp,
    const float* __restrict__ nc, const float* __restrict__ npd,
    const int* __restrict__ src, const int* __restrict__ dst,
    const float* __restrict__ W1, const float* __restrict__ b1,
    const float* __restrict__ W2, const float* __restrict__ b2,
    float* __restrict__ out, int nE)
{
    int lane = threadIdx.x & 63;
    int sub  = lane >> 4;      // which of 4 edges in this wave
    int g    = lane & 15;      // lane within edge group
    int d0   = g * 4;          // dims [d0, d0+4)
    int waveId = (blockIdx.x * 256 + threadIdx.x) >> 6;
    int nWaves = (gridDim.x * 256) >> 6;

    // Wave-invariant MLP params (L1-resident after first iteration).
    float4_t w1l = *reinterpret_cast<const float4_t*>(W1 + 128 * 64 + d0);
    float4_t b1v = *reinterpret_cast<const float4_t*>(b1 + d0);
    float4_t w2v = *reinterpret_cast<const float4_t*>(W2 + d0);
    float    b2v = b2[0];

    for (long e0 = (long)waveId * 4; e0 < nE; e0 += (long)nWaves * 4) {
        int e = (int)e0 + sub;
        bool valid = e < nE;
        int s = valid ? src[e] : 0;
        int t = valid ? dst[e] : 0;

        // cosine: dot of raw (bf16) embeddings / (fp32 norms)
        ushort4_t h4 = *reinterpret_cast<const ushort4_t*>(hbc + (long)s * 64 + d0);
        ushort4_t t4 = *reinterpret_cast<const ushort4_t*>(hbp + (long)t * 64 + d0);
        float dot = 0.f;
#pragma unroll
        for (int i = 0; i < 4; i++) dot += bf2f(h4[i]) * bf2f(t4[i]);
        dot += __shfl_xor(dot, 1);
        dot += __shfl_xor(dot, 2);
        dot += __shfl_xor(dot, 4);
        dot += __shfl_xor(dot, 8);

        float nh = nc[s], nt = npd[t];
        // exact reference eps semantics (hn = h/max(|h|,1e-12); denom eps 1e-8)
        float ih = 1.f / fmaxf(nh, 1e-12f);
        float it = 1.f / fmaxf(nt, 1e-12f);
        float denom = fmaxf((nh * ih) * (nt * it), 1e-8f);
        float cosv = dot * ih * it / denom;

        // x = relu(Pc[s] + Pp[t] + cos*W1[128] + b1); p = x @ W2
        ushort4_t pc4 = *reinterpret_cast<const ushort4_t*>(pc + (long)s * 64 + d0);
        ushort4_t pp4 = *reinterpret_cast<const ushort4_t*>(pp + (long)t * 64 + d0);
        float p = 0.f;
#pragma unroll
        for (int i = 0; i < 4; i++) {
            float x = bf2f(pc4[i]) + bf2f(pp4[i]) + cosv * w1l[i] + b1v[i];
            x = fmaxf(x, 0.f);
            p += x * w2v[i];
        }
        p += __shfl_xor(p, 1);
        p += __shfl_xor(p, 2);
        p += __shfl_xor(p, 4);
        p += __shfl_xor(p, 8);

        if (valid && g == 0)
            out[e] = 1.f / (1.f + expf(-(p + b2v)));
    }
}

extern "C" void kernel_launch(void* const* d_in, const int* in_sizes, int n_in,
                              void* d_out, int out_size, void* d_ws, size_t ws_size,
                              hipStream_t stream) {
    const float* h_c = (const float*)d_in[0];
    const float* h_p = (const float*)d_in[1];
    const int*   src = (const int*)d_in[2];
    const int*   dst = (const int*)d_in[3];
    const float* W1  = (const float*)d_in[4];
    const float* b1  = (const float*)d_in[5];
    const float* W2  = (const float*)d_in[6];
    const float* b2  = (const float*)d_in[7];
    float* out = (float*)d_out;

    int nC = in_sizes[0] / 64;
    int nP = in_sizes[1] / 64;
    int nE = in_sizes[2];

    // Workspace carve-up (256B aligned): ~52 MB total.
    char* ws = (char*)d_ws;
    size_t off = 0;
    auto carve = [&](size_t bytes) {
        void* p = ws + off;
        off = (off + bytes + 255) & ~(size_t)255;
        return p;
    };
    unsigned short* hbc = (unsigned short*)carve((size_t)nC * 64 * 2);
    unsigned short* hbp = (unsigned short*)carve((size_t)nP * 64 * 2);
    unsigned short* pcb = (unsigned short*)carve((size_t)nC * 64 * 2);
    unsigned short* ppb = (unsigned short*)carve((size_t)nP * 64 * 2);
    float* ncn = (float*)carve((size_t)nC * 4);
    float* npn = (float*)carve((size_t)nP * 4);

    convert_norm<<<(nC + 3) / 4, 256, 0, stream>>>(h_c, hbc, ncn, nC);
    convert_norm<<<(nP + 3) / 4, 256, 0, stream>>>(h_p, hbp, npn, nP);
    proj_mfma<<<(nC + 63) / 64, 256, 0, stream>>>(hbc, W1, pcb, nC, 0);
    proj_mfma<<<(nP + 63) / 64, 256, 0, stream>>>(hbp, W1, ppb, nP, 64);
    edge_mlp<<<1024, 256, 0, stream>>>(hbc, hbp, pcb, ppb, ncn, npn,
                                       src, dst, W1, b1, W2, b2, out, nE);
}

// Round 2
// 187.505 us; speedup vs baseline: 1.2812x; 1.2812x over previous
//
#include <hip/hip_runtime.h>
#include <math.h>

// ---------------------------------------------------------------------------
// Cosine_PredictingModule v2.
//   cat@W1 = heads@W1a + tails@W1b + cos*W1[128]  (per-node proj precompute).
//   K0 prep_w1: W1[0:128] -> bf16, pre-swizzled into MFMA B-fragment order.
//   K1 node_fused (1 dispatch, both tables): fp32 h -> LDS -> {bf16 table,
//      fp32 norms, bf16 proj via MFMA 16x16x32}.
//   K2 edge_mlp: 8 lanes/edge, 8 edges/wave, 16B gathers, full occupancy.
// ---------------------------------------------------------------------------

typedef __attribute__((ext_vector_type(8))) short bf16x8;
typedef __attribute__((ext_vector_type(4))) float f32x4;
typedef __attribute__((ext_vector_type(8))) unsigned short ushort8_t;
typedef __attribute__((ext_vector_type(4))) float float4_t;

__device__ __forceinline__ float bf2f(unsigned short u) {
    return __uint_as_float(((unsigned int)u) << 16);
}
__device__ __forceinline__ unsigned short f2bf(float f) {
    unsigned int x = __float_as_uint(f);
    return (unsigned short)((x + 0x7fffu + ((x >> 16) & 1u)) >> 16);
}

// K0: W1frag[half][nt][ks][lane][j] = bf16(W1[half*64 + ks*32 + (lane>>4)*8 + j][nt*16 + (lane&15)])
// so each MFMA wave loads its B-fragment as one contiguous 16B bf16x8.
__global__ __launch_bounds__(256) void prep_w1(
    const float* __restrict__ W1, unsigned short* __restrict__ frag)
{
    int idx = blockIdx.x * 256 + threadIdx.x;
    if (idx >= 2 * 4 * 2 * 64 * 8) return;
    int j    = idx & 7;
    int lane = (idx >> 3) & 63;
    int ks   = (idx >> 9) & 1;
    int nt   = (idx >> 10) & 3;
    int half = (idx >> 12) & 1;
    int k   = ks * 32 + (lane >> 4) * 8 + j;
    int col = nt * 16 + (lane & 15);
    frag[idx] = f2bf(W1[(half * 64 + k) * 64 + col]);
}

// K1: per block: 64 nodes. Stage fp32 -> LDS bf16, fp32 norms via 4-lane
// shuffle, bf16 table write, then 4 waves x 16 nodes of MFMA proj.
__global__ __launch_bounds__(256) void node_fused(
    const float* __restrict__ hc, const float* __restrict__ hp,
    const unsigned short* __restrict__ w1frag,
    unsigned short* __restrict__ hbc, unsigned short* __restrict__ hbp,
    unsigned short* __restrict__ pcb, unsigned short* __restrict__ ppb,
    float* __restrict__ ncn, float* __restrict__ npn,
    int nC, int nP, int blocksC)
{
    __shared__ unsigned short tile[64 * 64];   // 8 KB

    int b = blockIdx.x;
    const float* h; unsigned short *hb, *pj; float* nrm; int n, half;
    if (b < blocksC) { h = hc; hb = hbc; pj = pcb; nrm = ncn; n = nC; half = 0; }
    else { b -= blocksC; h = hp; hb = hbp; pj = ppb; nrm = npn; n = nP; half = 1; }

    int node0 = b * 64;
    int nloc  = min(64, n - node0);
    int t     = threadIdx.x;

    if (t * 16 < nloc * 64) {
        const float* src = h + (long)node0 * 64 + t * 16;
        float4_t v[4];
#pragma unroll
        for (int i = 0; i < 4; i++) v[i] = *reinterpret_cast<const float4_t*>(src + i * 4);

        float ss = 0.f;
#pragma unroll
        for (int i = 0; i < 4; i++)
#pragma unroll
            for (int j = 0; j < 4; j++) ss += v[i][j] * v[i][j];
        ss += __shfl_xor(ss, 1);
        ss += __shfl_xor(ss, 2);          // 4 threads per node
        if ((t & 3) == 0) nrm[node0 + (t >> 2)] = sqrtf(ss);

        ushort8_t u[2];
#pragma unroll
        for (int i = 0; i < 16; i++) u[i >> 3][i & 7] = f2bf(v[i >> 2][i & 3]);
        *reinterpret_cast<ushort8_t*>(&tile[t * 16])     = u[0];
        *reinterpret_cast<ushort8_t*>(&tile[t * 16 + 8]) = u[1];
        unsigned short* dst = hb + (long)node0 * 64 + t * 16;
        *reinterpret_cast<ushort8_t*>(dst)     = u[0];
        *reinterpret_cast<ushort8_t*>(dst + 8) = u[1];
    }
    __syncthreads();

    int wave = t >> 6, lane = t & 63;
    if (wave * 16 < nloc) {
        int m = lane & 15, quad = lane >> 4;
        bf16x8 a[2];
#pragma unroll
        for (int ks = 0; ks < 2; ks++)
            a[ks] = *reinterpret_cast<const bf16x8*>(
                &tile[(wave * 16 + m) * 64 + ks * 32 + quad * 8]);

        f32x4 acc[4];
#pragma unroll
        for (int nt = 0; nt < 4; nt++) acc[nt] = (f32x4){0.f, 0.f, 0.f, 0.f};
#pragma unroll
        for (int nt = 0; nt < 4; nt++)
#pragma unroll
            for (int ks = 0; ks < 2; ks++) {
                bf16x8 bf = *reinterpret_cast<const bf16x8*>(
                    &w1frag[(((half * 4 + nt) * 2 + ks) * 64 + lane) * 8]);
                acc[nt] = __builtin_amdgcn_mfma_f32_16x16x32_bf16(a[ks], bf, acc[nt], 0, 0, 0);
            }
        // C/D: col = lane&15, row = quad*4 + reg
#pragma unroll
        for (int nt = 0; nt < 4; nt++)
#pragma unroll
            for (int r = 0; r < 4; r++)
                pj[(long)(node0 + wave * 16 + quad * 4 + r) * 64 + nt * 16 + m]
                    = f2bf(acc[nt][r]);
    }
}

// K2: 8 lanes/edge, 8 edges/wave, 16B bf16x8 gathers.
__global__ __launch_bounds__(256) void edge_mlp(
    const unsigned short* __restrict__ hbc, const unsigned short* __restrict__ hbp,
    const unsigned short* __restrict__ pc,  const unsigned short* __restrict__ pp,
    const float* __restrict__ nc, const float* __restrict__ npd,
    const int* __restrict__ src, const int* __restrict__ dst,
    const float* __restrict__ W1, const float* __restrict__ b1,
    const float* __restrict__ W2, const float* __restrict__ b2,
    float* __restrict__ out, int nE)
{
    int lane = threadIdx.x & 63;
    int sub  = lane >> 3;      // edge within wave (0..7)
    int g    = lane & 7;       // lane within edge group
    int d0   = g * 8;          // dims [d0, d0+8)
    int waveId = (blockIdx.x * 256 + threadIdx.x) >> 6;
    int nWaves = (gridDim.x * 256) >> 6;

    float w1l[8], b1v[8], w2v[8];
#pragma unroll
    for (int i = 0; i < 8; i++) {
        w1l[i] = W1[128 * 64 + d0 + i];
        b1v[i] = b1[d0 + i];
        w2v[i] = W2[d0 + i];
    }
    float b2v = b2[0];

    for (long e0 = (long)waveId * 8; e0 < nE; e0 += (long)nWaves * 8) {
        int e = (int)e0 + sub;
        bool valid = e < nE;
        int s = valid ? src[e] : 0;
        int t = valid ? dst[e] : 0;

        ushort8_t h8 = *reinterpret_cast<const ushort8_t*>(hbc + (long)s * 64 + d0);
        ushort8_t t8 = *reinterpret_cast<const ushort8_t*>(hbp + (long)t * 64 + d0);
        float dot = 0.f;
#pragma unroll
        for (int i = 0; i < 8; i++) dot += bf2f(h8[i]) * bf2f(t8[i]);
        dot += __shfl_xor(dot, 1);
        dot += __shfl_xor(dot, 2);
        dot += __shfl_xor(dot, 4);

        float nh = nc[s], ntv = npd[t];
        float ih = 1.f / fmaxf(nh, 1e-12f);
        float it = 1.f / fmaxf(ntv, 1e-12f);
        float denom = fmaxf((nh * ih) * (ntv * it), 1e-8f);
        float cosv = dot * ih * it / denom;

        ushort8_t pc8 = *reinterpret_cast<const ushort8_t*>(pc + (long)s * 64 + d0);
        ushort8_t pp8 = *reinterpret_cast<const ushort8_t*>(pp + (long)t * 64 + d0);
        float p = 0.f;
#pragma unroll
        for (int i = 0; i < 8; i++) {
            float x = bf2f(pc8[i]) + bf2f(pp8[i]) + cosv * w1l[i] + b1v[i];
            x = fmaxf(x, 0.f);
            p += x * w2v[i];
        }
        p += __shfl_xor(p, 1);
        p += __shfl_xor(p, 2);
        p += __shfl_xor(p, 4);

        if (valid && g == 0)
            out[e] = 1.f / (1.f + expf(-(p + b2v)));
    }
}

extern "C" void kernel_launch(void* const* d_in, const int* in_sizes, int n_in,
                              void* d_out, int out_size, void* d_ws, size_t ws_size,
                              hipStream_t stream) {
    const float* h_c = (const float*)d_in[0];
    const float* h_p = (const float*)d_in[1];
    const int*   src = (const int*)d_in[2];
    const int*   dst = (const int*)d_in[3];
    const float* W1  = (const float*)d_in[4];
    const float* b1  = (const float*)d_in[5];
    const float* W2  = (const float*)d_in[6];
    const float* b2  = (const float*)d_in[7];
    float* out = (float*)d_out;

    int nC = in_sizes[0] / 64;
    int nP = in_sizes[1] / 64;
    int nE = in_sizes[2];

    char* ws = (char*)d_ws;
    size_t off = 0;
    auto carve = [&](size_t bytes) {
        void* p = ws + off;
        off = (off + bytes + 255) & ~(size_t)255;
        return p;
    };
    unsigned short* hbc = (unsigned short*)carve((size_t)nC * 64 * 2);
    unsigned short* hbp = (unsigned short*)carve((size_t)nP * 64 * 2);
    unsigned short* pcb = (unsigned short*)carve((size_t)nC * 64 * 2);
    unsigned short* ppb = (unsigned short*)carve((size_t)nP * 64 * 2);
    float* ncn = (float*)carve((size_t)nC * 4);
    float* npn = (float*)carve((size_t)nP * 4);
    unsigned short* w1f = (unsigned short*)carve((size_t)16384 * 2);

    prep_w1<<<64, 256, 0, stream>>>(W1, w1f);

    int blocksC = (nC + 63) / 64, blocksP = (nP + 63) / 64;
    node_fused<<<blocksC + blocksP, 256, 0, stream>>>(
        h_c, h_p, w1f, hbc, hbp, pcb, ppb, ncn, npn, nC, nP, blocksC);

    edge_mlp<<<2048, 256, 0, stream>>>(hbc, hbp, pcb, ppb, ncn, npn,
                                       src, dst, W1, b1, W2, b2, out, nE);
}

// Round 3
// 173.442 us; speedup vs baseline: 1.3851x; 1.0811x over previous
//
#include <hip/hip_runtime.h>
#include <math.h>

// ---------------------------------------------------------------------------
// Cosine_PredictingModule v3.
//   cat@W1 = heads@W1a + tails@W1b + cos*W1[128]  (per-node precompute).
//   Tables per node: hn = fp8(h/max(||h||,1e-12))  (64B)  — cosine path
//                    P  = bf16(h@W1half + b1?)     (128B) — MLP path
//   cos denom max(||hn||*||tn||,1e-8) ≈ 1 folded to 1 (error ~1e-7).
//   b1 folded into customer-side P.
//   K0 prep_w1: W1 -> bf16 MFMA B-fragment order (32KB, L2-hot).
//   K1 node_fused: fp32 h -> {fp8 hn table, bf16 P via MFMA}, coalesced
//      stores via padded-LDS transpose.
//   K2 edge_mlp: one-shot waves, 8 lanes/edge; per edge: 2x8B fp8 + 2x16B
//      bf16 gathers (384B/edge demand vs 512B in v2), no norm loads.
// ---------------------------------------------------------------------------

typedef __attribute__((ext_vector_type(8))) short bf16x8;
typedef __attribute__((ext_vector_type(4))) float f32x4;
typedef __attribute__((ext_vector_type(2))) float float2_t;
typedef __attribute__((ext_vector_type(8))) unsigned short ushort8_t;
typedef __attribute__((ext_vector_type(4))) float float4_t;
typedef __attribute__((ext_vector_type(4))) unsigned int uint4_t;
typedef __attribute__((ext_vector_type(2))) unsigned int uint2_t;

#define T_STRIDE 72   // A-tile LDS stride (ushorts): 144B rows, 16B aligned
#define P_STRIDE 72   // acc-transpose LDS stride

__device__ __forceinline__ float bf2f(unsigned short u) {
    return __uint_as_float(((unsigned int)u) << 16);
}
__device__ __forceinline__ unsigned short f2bf(float f) {
    unsigned int x = __float_as_uint(f);
    return (unsigned short)((x + 0x7fffu + ((x >> 16) & 1u)) >> 16);
}

// K0: W1frag[half][nt][ks][lane][j] =
//   bf16(W1[half*64 + ks*32 + (lane>>4)*8 + j][nt*16 + (lane&15)])
__global__ __launch_bounds__(256) void prep_w1(
    const float* __restrict__ W1, unsigned short* __restrict__ frag)
{
    int idx = blockIdx.x * 256 + threadIdx.x;
    if (idx >= 2 * 4 * 2 * 64 * 8) return;
    int j    = idx & 7;
    int lane = (idx >> 3) & 63;
    int ks   = (idx >> 9) & 1;
    int nt   = (idx >> 10) & 3;
    int half = (idx >> 12) & 1;
    int k   = ks * 32 + (lane >> 4) * 8 + j;
    int col = nt * 16 + (lane & 15);
    frag[idx] = f2bf(W1[(half * 64 + k) * 64 + col]);
}

// K1: 64 nodes/block.
__global__ __launch_bounds__(256) void node_fused(
    const float* __restrict__ hc, const float* __restrict__ hp,
    const unsigned short* __restrict__ w1frag, const float* __restrict__ b1,
    unsigned int* __restrict__ hnc, unsigned int* __restrict__ hnp,
    unsigned short* __restrict__ pcb, unsigned short* __restrict__ ppb,
    int nC, int nP, int blocksC)
{
    __shared__ unsigned short tile[64 * T_STRIDE];   // raw h bf16 (MFMA A)
    __shared__ unsigned short tile2[64 * P_STRIDE];  // P transpose buffer

    int b = blockIdx.x;
    const float* h; unsigned int* hn; unsigned short* pj; int n, half;
    if (b < blocksC) { h = hc; hn = hnc; pj = pcb; n = nC; half = 0; }
    else { b -= blocksC; h = hp; hn = hnp; pj = ppb; n = nP; half = 1; }

    int node0 = b * 64;
    int nloc  = min(64, n - node0);
    int t     = threadIdx.x;
    int nl    = t >> 2, q = t & 3;     // node-local, quarter (16 dims)

    if (nl < nloc) {
        const float* srcp = h + (long)(node0 + nl) * 64 + q * 16;
        float4_t v[4];
#pragma unroll
        for (int i = 0; i < 4; i++)
            v[i] = *reinterpret_cast<const float4_t*>(srcp + i * 4);

        float ss = 0.f;
#pragma unroll
        for (int i = 0; i < 4; i++)
#pragma unroll
            for (int j = 0; j < 4; j++) ss += v[i][j] * v[i][j];
        ss += __shfl_xor(ss, 1);
        ss += __shfl_xor(ss, 2);                     // 4 lanes per node
        float inv = 1.f / fmaxf(sqrtf(ss), 1e-12f);

        // fp8 e4m3 normalized row: 16 values -> 4 dwords, HW convert (RNE)
        uint4_t u8;
#pragma unroll
        for (int i = 0; i < 4; i++) {
            unsigned int d = __builtin_amdgcn_cvt_pk_fp8_f32(
                v[i][0] * inv, v[i][1] * inv, 0, false);
            d = __builtin_amdgcn_cvt_pk_fp8_f32(
                v[i][2] * inv, v[i][3] * inv, d, true);
            u8[i] = d;
        }
        *reinterpret_cast<uint4_t*>(hn + (long)(node0 + nl) * 16 + q * 4) = u8;

        // raw h -> bf16 LDS tile (MFMA A source)
        ushort8_t u[2];
#pragma unroll
        for (int i = 0; i < 16; i++) u[i >> 3][i & 7] = f2bf(v[i >> 2][i & 3]);
        *reinterpret_cast<ushort8_t*>(&tile[nl * T_STRIDE + q * 16])     = u[0];
        *reinterpret_cast<ushort8_t*>(&tile[nl * T_STRIDE + q * 16 + 8]) = u[1];
    }
    __syncthreads();

    int wave = t >> 6, lane = t & 63;
    int m = lane & 15, quad = lane >> 4;
    if (wave * 16 < nloc) {
        bf16x8 a[2];
#pragma unroll
        for (int ks = 0; ks < 2; ks++)
            a[ks] = *reinterpret_cast<const bf16x8*>(
                &tile[(wave * 16 + m) * T_STRIDE + ks * 32 + quad * 8]);

        f32x4 acc[4];
#pragma unroll
        for (int nt = 0; nt < 4; nt++) acc[nt] = (f32x4){0.f, 0.f, 0.f, 0.f};
#pragma unroll
        for (int nt = 0; nt < 4; nt++)
#pragma unroll
            for (int ks = 0; ks < 2; ks++) {
                bf16x8 bf = *reinterpret_cast<const bf16x8*>(
                    &w1frag[(((half * 4 + nt) * 2 + ks) * 64 + lane) * 8]);
                acc[nt] = __builtin_amdgcn_mfma_f32_16x16x32_bf16(
                    a[ks], bf, acc[nt], 0, 0, 0);
            }
        if (half == 0) {     // fold b1 into customer-side P
#pragma unroll
            for (int nt = 0; nt < 4; nt++) {
                float bb = b1[nt * 16 + m];
#pragma unroll
                for (int r = 0; r < 4; r++) acc[nt][r] += bb;
            }
        }
        // C/D: col = lane&15, row = quad*4 + reg -> LDS transpose
#pragma unroll
        for (int nt = 0; nt < 4; nt++)
#pragma unroll
            for (int r = 0; r < 4; r++)
                tile2[(wave * 16 + quad * 4 + r) * P_STRIDE + nt * 16 + m]
                    = f2bf(acc[nt][r]);
    }
    __syncthreads();

    if (nl < nloc) {   // coalesced 16B P stores
        ushort8_t p0 = *reinterpret_cast<ushort8_t*>(&tile2[nl * P_STRIDE + q * 16]);
        ushort8_t p1 = *reinterpret_cast<ushort8_t*>(&tile2[nl * P_STRIDE + q * 16 + 8]);
        unsigned short* dstp = pj + (long)(node0 + nl) * 64 + q * 16;
        *reinterpret_cast<ushort8_t*>(dstp)     = p0;
        *reinterpret_cast<ushort8_t*>(dstp + 8) = p1;
    }
}

// K2: one-shot, 8 lanes/edge, 8 edges/wave.
__global__ __launch_bounds__(256) void edge_mlp(
    const unsigned int* __restrict__ hnc, const unsigned int* __restrict__ hnp,
    const unsigned short* __restrict__ pc, const unsigned short* __restrict__ pp,
    const int* __restrict__ src, const int* __restrict__ dst,
    const float* __restrict__ W1, const float* __restrict__ W2,
    const float* __restrict__ b2, float* __restrict__ out, int nE)
{
    int lane = threadIdx.x & 63;
    int sub  = lane >> 3;
    int g    = lane & 7;
    int d0   = g * 8;
    int e    = ((blockIdx.x * 256 + threadIdx.x) >> 6) * 8 + sub;
    bool valid = e < nE;
    int s = valid ? src[e] : 0;
    int t = valid ? dst[e] : 0;

    float4_t w1a = *reinterpret_cast<const float4_t*>(W1 + 128 * 64 + d0);
    float4_t w1b = *reinterpret_cast<const float4_t*>(W1 + 128 * 64 + d0 + 4);
    float4_t w2a = *reinterpret_cast<const float4_t*>(W2 + d0);
    float4_t w2b = *reinterpret_cast<const float4_t*>(W2 + d0 + 4);
    float b2v = b2[0];

    uint2_t hs = *reinterpret_cast<const uint2_t*>(hnc + (long)s * 16 + g * 2);
    uint2_t ht = *reinterpret_cast<const uint2_t*>(hnp + (long)t * 16 + g * 2);
    ushort8_t ps8 = *reinterpret_cast<const ushort8_t*>(pc + (long)s * 64 + d0);
    ushort8_t pt8 = *reinterpret_cast<const ushort8_t*>(pp + (long)t * 64 + d0);

    float hsv[8], htv[8];
#pragma unroll
    for (int w = 0; w < 2; w++) {
        float2_t lo = __builtin_amdgcn_cvt_pk_f32_fp8((int)hs[w], false);
        float2_t hi = __builtin_amdgcn_cvt_pk_f32_fp8((int)hs[w], true);
        hsv[w*4+0] = lo[0]; hsv[w*4+1] = lo[1]; hsv[w*4+2] = hi[0]; hsv[w*4+3] = hi[1];
        float2_t lo2 = __builtin_amdgcn_cvt_pk_f32_fp8((int)ht[w], false);
        float2_t hi2 = __builtin_amdgcn_cvt_pk_f32_fp8((int)ht[w], true);
        htv[w*4+0] = lo2[0]; htv[w*4+1] = lo2[1]; htv[w*4+2] = hi2[0]; htv[w*4+3] = hi2[1];
    }

    float dot = 0.f;
#pragma unroll
    for (int i = 0; i < 8; i++) dot += hsv[i] * htv[i];
    dot += __shfl_xor(dot, 1);
    dot += __shfl_xor(dot, 2);
    dot += __shfl_xor(dot, 4);
    float cosv = dot;                    // denom folded (≈1 to 1e-7)

    float w1l[8] = {w1a[0], w1a[1], w1a[2], w1a[3], w1b[0], w1b[1], w1b[2], w1b[3]};
    float w2v[8] = {w2a[0], w2a[1], w2a[2], w2a[3], w2b[0], w2b[1], w2b[2], w2b[3]};
    float p = 0.f;
#pragma unroll
    for (int i = 0; i < 8; i++) {
        float x = bf2f(ps8[i]) + bf2f(pt8[i]) + cosv * w1l[i];  // b1 folded
        x = fmaxf(x, 0.f);
        p += x * w2v[i];
    }
    p += __shfl_xor(p, 1);
    p += __shfl_xor(p, 2);
    p += __shfl_xor(p, 4);

    if (valid && g == 0)
        out[e] = 1.f / (1.f + expf(-(p + b2v)));
}

extern "C" void kernel_launch(void* const* d_in, const int* in_sizes, int n_in,
                              void* d_out, int out_size, void* d_ws, size_t ws_size,
                              hipStream_t stream) {
    const float* h_c = (const float*)d_in[0];
    const float* h_p = (const float*)d_in[1];
    const int*   src = (const int*)d_in[2];
    const int*   dst = (const int*)d_in[3];
    const float* W1  = (const float*)d_in[4];
    const float* b1  = (const float*)d_in[5];
    const float* W2  = (const float*)d_in[6];
    const float* b2  = (const float*)d_in[7];
    float* out = (float*)d_out;

    int nC = in_sizes[0] / 64;
    int nP = in_sizes[1] / 64;
    int nE = in_sizes[2];

    char* ws = (char*)d_ws;
    size_t off = 0;
    auto carve = [&](size_t bytes) {
        void* p = ws + off;
        off = (off + bytes + 255) & ~(size_t)255;
        return p;
    };
    unsigned int*   hnc = (unsigned int*)carve((size_t)nC * 64);        // fp8
    unsigned int*   hnp = (unsigned int*)carve((size_t)nP * 64);        // fp8
    unsigned short* pcb = (unsigned short*)carve((size_t)nC * 64 * 2);  // bf16
    unsigned short* ppb = (unsigned short*)carve((size_t)nP * 64 * 2);  // bf16
    unsigned short* w1f = (unsigned short*)carve((size_t)16384 * 2);

    prep_w1<<<64, 256, 0, stream>>>(W1, w1f);

    int blocksC = (nC + 63) / 64, blocksP = (nP + 63) / 64;
    node_fused<<<blocksC + blocksP, 256, 0, stream>>>(
        h_c, h_p, w1f, b1, hnc, hnp, pcb, ppb, nC, nP, blocksC);

    edge_mlp<<<(nE + 31) / 32, 256, 0, stream>>>(
        hnc, hnp, pcb, ppb, src, dst, W1, W2, b2, out, nE);
}